// Round 1
// baseline (1055.784 us; speedup 1.0000x reference)
//
#include <hip/hip_runtime.h>

// Problem constants (match reference)
namespace {
constexpr int kB = 16;
constexpr int kN = 2000;
constexpr int kNP = 2048;   // padded to pow2 for bitonic sort
constexpr int kH = 512;
constexpr int kW = 512;
constexpr int kMaxDet = 10;
constexpr int kTopK = 5;
constexpr float kConfT = 0.2f;
}

// Exact test for fl32(inter/denom) > 0.4f without doing the division:
//   RN(q) > 0.4f  <=>  q >= M, M = midpoint(0.4f, nextafterf(0.4f, +inf))
// (nextup(0.4f)=0x3ECCCCCE has even mantissa, so the tie rounds up — include equality).
// M*denom in double adds ~1e-16 rel error vs the exact real product — negligible.
__device__ __forceinline__ bool iou_suppress(
    float ax1, float ay1, float ax2, float ay2, float aA,
    float bx1, float by1, float bx2, float by2, float bA, double M)
{
    float ix1 = fmaxf(ax1, bx1), iy1 = fmaxf(ay1, by1);
    float ix2 = fminf(ax2, bx2), iy2 = fminf(ay2, by2);
    float iw = fmaxf(ix2 - ix1, 0.0f), ih = fmaxf(iy2 - iy1, 0.0f);
    // __f*_rn intrinsics: forbid FMA contraction so rounding matches numpy exactly
    float inter = __fmul_rn(iw, ih);
    float denom = __fadd_rn(__fsub_rn(__fadd_rn(aA, bA), inter), 1e-9f);
    return (double)inter >= M * (double)denom;
}

// One workgroup per image: sort + exact greedy NMS + selection + 10-box stage.
__global__ __launch_bounds__(1024) void nms_kernel(
    const float* __restrict__ rbox,   // [B, N, 5]  x1 y1 x2 y2 conf
    const float* __restrict__ negb,   // [B, 10, 5]
    float* __restrict__ out,          // [B*H*W] mask | [B*10*4] tboxes | [B*10] keep2
    int* __restrict__ ws)             // [B, 10, 5] int: x1 y1 x2 y2 keep2  (for paint)
{
    __shared__ unsigned long long keys[kNP];                         // 16 KB (reused as areas)
    __shared__ float sx1[kNP], sy1[kNP], sx2[kNP], sy2[kNP], sc[kNP]; // 40 KB
    __shared__ unsigned char dead[kNP], kept[kNP];                   // 4 KB
    __shared__ unsigned long long intra[64];
    __shared__ int chunkIdx[64];
    __shared__ int chunkCnt;
    __shared__ int hasConfSh;
    __shared__ int kidxSh[kMaxDet];
    __shared__ int numSlotsSh;

    const int b = blockIdx.x;
    const int tid = (int)threadIdx.x;
    const int nt = (int)blockDim.x;
    const double M = 0.5 * ((double)0.4f + (double)__uint_as_float(0x3ECCCCCEu));
    const float* rb = rbox + (size_t)b * kN * 5;

    // ---- build stable-descending sort keys: (ordered score)<<32 | (~idx) ----
    for (int i = tid; i < kNP; i += nt) {
        unsigned long long key = 0ull;
        if (i < kN) {
            unsigned u = __float_as_uint(rb[i * 5 + 4]);
            u = (u & 0x80000000u) ? ~u : (u | 0x80000000u);   // order-preserving
            key = ((unsigned long long)u << 32) |
                  (unsigned long long)(0xFFFFFFFFu - (unsigned)i); // smaller idx wins ties
        }
        keys[i] = key;   // pads = 0 -> sink to end in descending sort
        dead[i] = 0; kept[i] = 0;
    }
    __syncthreads();

    // ---- bitonic sort, descending (direction flipped vs ascending network) ----
    for (int k = 2; k <= kNP; k <<= 1) {
        for (int j = k >> 1; j > 0; j >>= 1) {
            for (int i = tid; i < kNP; i += nt) {
                int ixj = i ^ j;
                if (ixj > i) {
                    bool up = ((i & k) != 0);
                    unsigned long long a = keys[i], c = keys[ixj];
                    if ((a > c) == up) { keys[i] = c; keys[ixj] = a; }
                }
            }
            __syncthreads();
        }
    }

    // ---- gather boxes in sorted order ----
    for (int s = tid; s < kNP; s += nt) {
        if (s < kN) {
            unsigned idx = 0xFFFFFFFFu - (unsigned)(keys[s] & 0xFFFFFFFFull);
            const float* p = rb + (size_t)idx * 5;
            sx1[s] = p[0]; sy1[s] = p[1]; sx2[s] = p[2]; sy2[s] = p[3]; sc[s] = p[4];
        } else {
            sx1[s] = 0.f; sy1[s] = 0.f; sx2[s] = 0.f; sy2[s] = 0.f; sc[s] = -1.f;
        }
    }
    __syncthreads();

    // keys region no longer needed -> reuse as per-box areas
    float* sar = (float*)keys;
    for (int s = tid; s < kNP; s += nt)
        sar[s] = fmaxf(sx2[s] - sx1[s], 0.f) * fmaxf(sy2[s] - sy1[s], 0.f);
    if (tid == 0) hasConfSh = (sc[0] > kConfT) ? 1 : 0;   // sorted desc -> max score first
    __syncthreads();
    const float confThres = hasConfSh ? kConfT : 0.0f;

    // ---- exact greedy NMS, 64-row chunks ----
    for (int c0 = 0; c0 < kN; c0 += 64) {
        // step 1: intra-chunk suppression bitmasks (row i -> bits of later rows in chunk)
        if (tid < 64) {
            int i = c0 + tid;
            unsigned long long m = 0ull;
            if (i < kN) {
                float ax1 = sx1[i], ay1 = sy1[i], ax2 = sx2[i], ay2 = sy2[i], aA = sar[i];
                int jend = min(64, kN - c0);
                for (int jj = tid + 1; jj < jend; ++jj) {
                    int j = c0 + jj;
                    if (iou_suppress(ax1, ay1, ax2, ay2, aA,
                                     sx1[j], sy1[j], sx2[j], sy2[j], sar[j], M))
                        m |= 1ull << jj;
                }
            }
            intra[tid] = m;
        }
        __syncthreads();

        // step 2: serial resolve of the 64-row chain (tiny)
        if (tid == 0) {
            int cend = min(64, kN - c0);
            unsigned long long kill = 0ull;
            for (int ii = 0; ii < cend; ++ii)
                if (dead[c0 + ii] || !(sc[c0 + ii] > confThres)) kill |= 1ull << ii;
            unsigned long long sup = 0ull;
            int cnt = 0;
            for (int ii = 0; ii < cend; ++ii) {
                if (!(((kill | sup) >> ii) & 1ull)) {
                    kept[c0 + ii] = 1;
                    chunkIdx[cnt++] = c0 + ii;
                    sup |= intra[ii];
                }
            }
            chunkCnt = cnt;
        }
        __syncthreads();

        // step 3: chunk survivors suppress all later columns (parallel over j)
        int cc = chunkCnt;
        if (cc > 0) {
            for (int j = c0 + 64 + tid; j < kN; j += nt) {
                if (dead[j]) continue;
                float bx1 = sx1[j], by1 = sy1[j], bx2 = sx2[j], by2 = sy2[j], bA = sar[j];
                bool killj = false;
                for (int t = 0; t < cc; ++t) {
                    int i = chunkIdx[t];
                    if (iou_suppress(sx1[i], sy1[i], sx2[i], sy2[i], sar[i],
                                     bx1, by1, bx2, by2, bA, M)) { killj = true; break; }
                }
                if (killj) dead[j] = 1;
            }
        }
        __syncthreads();
    }

    // ---- tiny filter (applied AFTER NMS, as in reference) ----
    for (int i = tid; i < kN; i += nt) {
        if (kept[i] && !((sx2[i] - sx1[i] >= 1.0f) && (sy2[i] - sy1[i] >= 1.0f)))
            kept[i] = 0;
    }
    __syncthreads();

    // ---- select first min(count, limit) kept (limit=10, or 5 on the no-conf branch) ----
    if (tid == 0) {
        int limit = hasConfSh ? kMaxDet : kTopK;
        int cnt = 0;
        for (int i = 0; i < kN && cnt < limit; ++i)
            if (kept[i]) kidxSh[cnt++] = i;
        numSlotsSh = cnt;
    }
    __syncthreads();

    // ---- 10-box stage: combine with neg, stable sort by conf desc, greedy NMS, emit ----
    if (tid == 0) {
        float comb[kMaxDet][5];
        const float* ng = negb + (size_t)b * kMaxDet * 5;
        int ns = numSlotsSh;
        for (int s = 0; s < kMaxDet; ++s) {
            if (s < ns) {
                int i = kidxSh[s];
                comb[s][0] = sx1[i]; comb[s][1] = sy1[i];
                comb[s][2] = sx2[i]; comb[s][3] = sy2[i]; comb[s][4] = sc[i];
            } else {
                #pragma unroll
                for (int c = 0; c < 5; ++c) comb[s][c] = ng[s * 5 + c];
            }
        }
        // stable insertion sort, descending conf (== jnp.argsort(-conf, stable))
        int ord[kMaxDet];
        for (int s = 0; s < kMaxDet; ++s) ord[s] = s;
        for (int s = 1; s < kMaxDet; ++s) {
            int cur = ord[s]; float cv = comb[cur][4];
            int t = s - 1;
            while (t >= 0 && comb[ord[t]][4] < cv) { ord[t + 1] = ord[t]; --t; }
            ord[t + 1] = cur;
        }
        float cb[kMaxDet][5];
        for (int s = 0; s < kMaxDet; ++s)
            for (int c = 0; c < 5; ++c) cb[s][c] = comb[ord[s]][c];
        int k2[kMaxDet];
        float ar2[kMaxDet];
        for (int s = 0; s < kMaxDet; ++s) {
            k2[s] = (cb[s][4] > 0.0f) ? 1 : 0;
            ar2[s] = fmaxf(cb[s][2] - cb[s][0], 0.f) * fmaxf(cb[s][3] - cb[s][1], 0.f);
        }
        for (int i = 0; i < kMaxDet; ++i) {
            if (!k2[i]) continue;
            for (int j = i + 1; j < kMaxDet; ++j) {
                if (iou_suppress(cb[i][0], cb[i][1], cb[i][2], cb[i][3], ar2[i],
                                 cb[j][0], cb[j][1], cb[j][2], cb[j][3], ar2[j], M))
                    k2[j] = 0;
            }
        }
        float* tb = out + (size_t)kB * kH * kW + (size_t)b * kMaxDet * 4;
        float* kp = out + (size_t)kB * kH * kW + (size_t)kB * kMaxDet * 4 + (size_t)b * kMaxDet;
        int* wsb = ws + b * kMaxDet * 5;
        for (int s = 0; s < kMaxDet; ++s) {
            for (int c = 0; c < 4; ++c) tb[s * 4 + c] = k2[s] ? cb[s][c] : 0.0f;
            kp[s] = k2[s] ? 1.0f : 0.0f;
            wsb[s * 5 + 0] = (int)floorf(cb[s][0] + 0.5f);
            wsb[s * 5 + 1] = (int)floorf(cb[s][1] + 0.5f);
            wsb[s * 5 + 2] = (int)floorf(cb[s][2] + 0.5f);
            wsb[s * 5 + 3] = (int)floorf(cb[s][3] + 0.5f);
            wsb[s * 5 + 4] = k2[s];
        }
    }
}

// mask_map = 1.0 where NOT covered by any kept box, else 0.0. float4 stores.
__global__ __launch_bounds__(256) void paint_kernel(
    const int* __restrict__ ws, float* __restrict__ out)
{
    int gid = blockIdx.x * 256 + (int)threadIdx.x;  // 16*512*128 threads, 4 px each
    int b = gid >> 16;           // 512*128 = 65536 quads per image
    int rem = gid & 65535;
    int y = rem >> 7;
    int x0 = (rem & 127) << 2;
    const int* wb = ws + b * kMaxDet * 5;
    float o0 = 1.f, o1 = 1.f, o2 = 1.f, o3 = 1.f;
    #pragma unroll
    for (int s = 0; s < kMaxDet; ++s) {
        int k = wb[s * 5 + 4];
        int y1 = wb[s * 5 + 1], y2 = wb[s * 5 + 3];
        if (k && y >= y1 && y < y2) {
            int x1 = wb[s * 5 + 0], x2 = wb[s * 5 + 2];
            if (x0 + 0 >= x1 && x0 + 0 < x2) o0 = 0.f;
            if (x0 + 1 >= x1 && x0 + 1 < x2) o1 = 0.f;
            if (x0 + 2 >= x1 && x0 + 2 < x2) o2 = 0.f;
            if (x0 + 3 >= x1 && x0 + 3 < x2) o3 = 0.f;
        }
    }
    float4 v = make_float4(o0, o1, o2, o3);
    *((float4*)(out + ((size_t)b << 18) + (y << 9) + x0)) = v;
}

extern "C" void kernel_launch(void* const* d_in, const int* in_sizes, int n_in,
                              void* d_out, int out_size, void* d_ws, size_t ws_size,
                              hipStream_t stream)
{
    (void)in_sizes; (void)n_in; (void)out_size; (void)ws_size;
    const float* rbox = (const float*)d_in[1];   // region_boxes [16,2000,5]
    const float* negb = (const float*)d_in[2];   // neg_boxes   [16,10,5]
    float* out = (float*)d_out;
    int* ws = (int*)d_ws;
    hipLaunchKernelGGL(nms_kernel, dim3(kB), dim3(1024), 0, stream, rbox, negb, out, ws);
    hipLaunchKernelGGL(paint_kernel, dim3((kB * kH * kW / 4) / 256), dim3(256), 0, stream,
                       ws, out);
}

// Round 2
// 290.718 us; speedup vs baseline: 3.6316x; 3.6316x over previous
//
#include <hip/hip_runtime.h>

namespace {
constexpr int kB = 16;
constexpr int kN = 2000;
constexpr int kNP = 2048;   // padded to pow2 for bitonic sort
constexpr int kNW = kNP / 64;  // 32 u64 words per suppression row
constexpr int kH = 512;
constexpr int kW = 512;
constexpr int kMaxDet = 10;
constexpr int kTopK = 5;
constexpr float kConfT = 0.2f;

// ws layout (bytes)
constexpr size_t OFF_SORT  = 0;                           // float[16][6][2048]: x1,y1,x2,y2,conf,area
constexpr size_t SZ_SORT   = (size_t)kB * 6 * kNP * 4;    // 786432
constexpr size_t OFF_PAINT = OFF_SORT + SZ_SORT;          // int[16][10][5]
constexpr size_t OFF_MASK  = 1ull << 20;                  // u64[16][32][2048] (word-major: [b][w][i])
constexpr size_t SZ_MASK   = (size_t)kB * kNW * kNP * 8;  // 8 MB
constexpr size_t WS_NEEDED = OFF_MASK + SZ_MASK;
}

// Exact test for fl32(inter/denom) > 0.4f without doing the division:
//   RN(q) > 0.4f  <=>  q >= M, M = midpoint(0.4f, nextafterf(0.4f, +inf))
__device__ __forceinline__ double thrM() {
    return 0.5 * ((double)0.4f + (double)__uint_as_float(0x3ECCCCCEu));
}

__device__ __forceinline__ bool iou_suppress(
    float ax1, float ay1, float ax2, float ay2, float aA,
    float bx1, float by1, float bx2, float by2, float bA, double M)
{
    float ix1 = fmaxf(ax1, bx1), iy1 = fmaxf(ay1, by1);
    float ix2 = fminf(ax2, bx2), iy2 = fminf(iy2 = ay2, by2);
    // NOTE: keep exact op order; __f*_rn forbids FMA contraction
    ix2 = fminf(ax2, bx2); iy2 = fminf(ay2, by2);
    float iw = fmaxf(ix2 - ix1, 0.0f), ih = fmaxf(iy2 - iy1, 0.0f);
    float inter = __fmul_rn(iw, ih);
    float denom = __fadd_rn(__fsub_rn(__fadd_rn(aA, bA), inter), 1e-9f);
    return (double)inter >= M * (double)denom;
}

// ---------------- kernel 1: per-image stable descending sort ----------------
__global__ __launch_bounds__(1024) void sort_kernel(
    const float* __restrict__ rbox, float* __restrict__ S)
{
    __shared__ unsigned long long keys[kNP];
    const int b = blockIdx.x, tid = (int)threadIdx.x, nt = (int)blockDim.x;
    const float* rb = rbox + (size_t)b * kN * 5;

    for (int i = tid; i < kNP; i += nt) {
        unsigned long long key = 0ull;
        if (i < kN) {
            unsigned u = __float_as_uint(rb[i * 5 + 4]);
            u = (u & 0x80000000u) ? ~u : (u | 0x80000000u);   // order-preserving map
            key = ((unsigned long long)u << 32) |
                  (unsigned long long)(0xFFFFFFFFu - (unsigned)i); // smaller idx wins ties
        }
        keys[i] = key;  // pads sink to the end in descending order
    }
    __syncthreads();

    for (int k = 2; k <= kNP; k <<= 1) {
        for (int j = k >> 1; j > 0; j >>= 1) {
            for (int i = tid; i < kNP; i += nt) {
                int ixj = i ^ j;
                if (ixj > i) {
                    bool up = ((i & k) != 0);
                    unsigned long long a = keys[i], c = keys[ixj];
                    if ((a > c) == up) { keys[i] = c; keys[ixj] = a; }
                }
            }
            __syncthreads();
        }
    }

    float* Sb = S + (size_t)b * 6 * kNP;
    for (int s = tid; s < kNP; s += nt) {
        float x1 = 0.f, y1 = 0.f, x2 = 0.f, y2 = 0.f, c = -1.f;
        if (s < kN) {
            unsigned idx = 0xFFFFFFFFu - (unsigned)(keys[s] & 0xFFFFFFFFull);
            const float* p = rb + (size_t)idx * 5;
            x1 = p[0]; y1 = p[1]; x2 = p[2]; y2 = p[3]; c = p[4];
        }
        Sb[0 * kNP + s] = x1; Sb[1 * kNP + s] = y1;
        Sb[2 * kNP + s] = x2; Sb[3 * kNP + s] = y2;
        Sb[4 * kNP + s] = c;
        Sb[5 * kNP + s] = __fmul_rn(fmaxf(x2 - x1, 0.f), fmaxf(y2 - y1, 0.f));
    }
}

// ------------- kernel 2: suppression bit-matrix, whole chip -------------
// mask[b][jb][i] (u64): bit jj set iff j=jb*64+jj > i and iou(i,j) > 0.4
__global__ __launch_bounds__(256) void mask_kernel(
    const float* __restrict__ S, unsigned long long* __restrict__ Mk)
{
    __shared__ float cx1[64], cy1[64], cx2[64], cy2[64], car[64];
    const int b = blockIdx.z, jb = (int)blockIdx.x, ibg = (int)blockIdx.y;
    const int t = (int)threadIdx.x;
    const float* Sb = S + (size_t)b * 6 * kNP;

    if (t < 64) {
        int j = jb * 64 + t;
        cx1[t] = Sb[0 * kNP + j]; cy1[t] = Sb[1 * kNP + j];
        cx2[t] = Sb[2 * kNP + j]; cy2[t] = Sb[3 * kNP + j];
        car[t] = Sb[5 * kNP + j];
    }
    __syncthreads();

    const int i = ibg * 256 + t;
    const int j0 = jb * 64;
    unsigned long long w = 0ull;
    if (i < j0 + 63) {   // otherwise no j>i in this word -> zero
        float ax1 = Sb[0 * kNP + i], ay1 = Sb[1 * kNP + i];
        float ax2 = Sb[2 * kNP + i], ay2 = Sb[3 * kNP + i];
        float aA  = Sb[5 * kNP + i];
        const double M = thrM();
        #pragma unroll 8
        for (int jj = 0; jj < 64; ++jj) {
            int j = j0 + jj;
            if (j > i && iou_suppress(ax1, ay1, ax2, ay2, aA,
                                      cx1[jj], cy1[jj], cx2[jj], cy2[jj], car[jj], M))
                w |= 1ull << jj;
        }
    }
    Mk[((size_t)(b * kNW + jb)) * kNP + i] = w;   // coalesced 8B stores
}

// ------------- kernel 3: greedy resolve + selection + 10-box stage -------------
__global__ __launch_bounds__(64) void resolve_kernel(
    const float* __restrict__ S, const unsigned long long* __restrict__ Mk,
    const float* __restrict__ negb, float* __restrict__ out, int* __restrict__ paint)
{
    const int b = blockIdx.x;
    const int lane = (int)threadIdx.x;
    const float* Sb = S + (size_t)b * 6 * kNP;
    const unsigned long long* Mb = Mk + (size_t)b * kNW * kNP;
    const double M = thrM();

    const float conf0 = Sb[4 * kNP + 0];           // sorted desc -> max score
    const int hasConf = conf0 > kConfT;
    const float confThres = hasConf ? kConfT : 0.0f;

    // per-word valid/tiny bitmasks, owner = lane w (<32)
    unsigned long long validw = 0ull, tinyw = 0ull;
    for (int wb = 0; wb < kNW; ++wb) {
        int j = wb * 64 + lane;
        unsigned long long mv = __ballot(Sb[4 * kNP + j] > confThres);
        unsigned long long mt = __ballot((Sb[2 * kNP + j] - Sb[0 * kNP + j] >= 1.0f) &&
                                         (Sb[3 * kNP + j] - Sb[1 * kNP + j] >= 1.0f));
        if (lane == wb) { validw = mv; tinyw = mt; }
    }

    // greedy scan: dead set distributed, lane w owns word w.
    unsigned long long deadw = 0ull;
    unsigned long long aliveW = 0ull;     // alive bits of current 64-row window (uniform)
    constexpr int BK = 20;                // 2000 = 100 blocks of 20 rows
    unsigned long long buf0[BK], buf1[BK];
    const bool ld = lane < kNW;
    const unsigned long long* lrow = Mb + (size_t)lane * kNP;

    #pragma unroll
    for (int k = 0; k < BK; ++k) buf0[k] = ld ? lrow[k] : 0ull;

    for (int bb = 0; bb < 100; bb += 2) {
        { // prefetch block bb+1
            int base = (bb + 1) * BK;
            #pragma unroll
            for (int k = 0; k < BK; ++k) buf1[k] = ld ? lrow[base + k] : 0ull;
        }
        { // process block bb
            int base = bb * BK;
            unsigned long long rowsel[BK];
            #pragma unroll
            for (int k = 0; k < BK; ++k) rowsel[k] = __shfl(buf0[k], (base + k) >> 6);
            #pragma unroll
            for (int k = 0; k < BK; ++k) {
                int i = base + k;
                if ((i & 63) == 0) aliveW = __shfl(validw & ~deadw, i >> 6);
                if ((aliveW >> (i & 63)) & 1ull) { deadw |= buf0[k]; aliveW &= ~rowsel[k]; }
            }
        }
        if (bb + 2 < 100) { // prefetch block bb+2
            int base = (bb + 2) * BK;
            #pragma unroll
            for (int k = 0; k < BK; ++k) buf0[k] = ld ? lrow[base + k] : 0ull;
        }
        { // process block bb+1
            int base = (bb + 1) * BK;
            unsigned long long rowsel[BK];
            #pragma unroll
            for (int k = 0; k < BK; ++k) rowsel[k] = __shfl(buf1[k], (base + k) >> 6);
            #pragma unroll
            for (int k = 0; k < BK; ++k) {
                int i = base + k;
                if ((i & 63) == 0) aliveW = __shfl(validw & ~deadw, i >> 6);
                if ((aliveW >> (i & 63)) & 1ull) { deadw |= buf1[k]; aliveW &= ~rowsel[k]; }
            }
        }
    }

    unsigned long long keptw = validw & ~deadw & tinyw;   // tiny filter AFTER NMS
    __shared__ unsigned long long keptSh[kNW];
    if (lane < kNW) keptSh[lane] = keptw;
    __syncthreads();

    if (lane == 0) {
        const int limit = hasConf ? kMaxDet : kTopK;
        int kidx[kMaxDet];
        int cnt = 0;
        for (int w = 0; w < kNW && cnt < limit; ++w) {
            unsigned long long kw = keptSh[w];
            while (kw && cnt < limit) {
                int bit = __ffsll((long long)kw) - 1;
                kidx[cnt++] = w * 64 + bit;
                kw &= kw - 1;
            }
        }

        // ---- 10-box stage: combine with neg, stable sort by conf desc, greedy NMS ----
        float comb[kMaxDet][5];
        const float* ng = negb + (size_t)b * kMaxDet * 5;
        for (int s = 0; s < kMaxDet; ++s) {
            if (s < cnt) {
                int i = kidx[s];
                comb[s][0] = Sb[0 * kNP + i]; comb[s][1] = Sb[1 * kNP + i];
                comb[s][2] = Sb[2 * kNP + i]; comb[s][3] = Sb[3 * kNP + i];
                comb[s][4] = Sb[4 * kNP + i];
            } else {
                #pragma unroll
                for (int c = 0; c < 5; ++c) comb[s][c] = ng[s * 5 + c];
            }
        }
        // stable insertion sort, descending conf (== jnp.argsort(-conf, stable))
        int ord[kMaxDet];
        for (int s = 0; s < kMaxDet; ++s) ord[s] = s;
        for (int s = 1; s < kMaxDet; ++s) {
            int cur = ord[s]; float cv = comb[cur][4];
            int t = s - 1;
            while (t >= 0 && comb[ord[t]][4] < cv) { ord[t + 1] = ord[t]; --t; }
            ord[t + 1] = cur;
        }
        float cb[kMaxDet][5];
        for (int s = 0; s < kMaxDet; ++s)
            for (int c = 0; c < 5; ++c) cb[s][c] = comb[ord[s]][c];
        int k2[kMaxDet];
        float ar2[kMaxDet];
        for (int s = 0; s < kMaxDet; ++s) {
            k2[s] = (cb[s][4] > 0.0f) ? 1 : 0;
            ar2[s] = fmaxf(cb[s][2] - cb[s][0], 0.f) * fmaxf(cb[s][3] - cb[s][1], 0.f);
        }
        for (int i = 0; i < kMaxDet; ++i) {
            if (!k2[i]) continue;
            for (int j = i + 1; j < kMaxDet; ++j) {
                if (iou_suppress(cb[i][0], cb[i][1], cb[i][2], cb[i][3], ar2[i],
                                 cb[j][0], cb[j][1], cb[j][2], cb[j][3], ar2[j], M))
                    k2[j] = 0;
            }
        }
        float* tb = out + (size_t)kB * kH * kW + (size_t)b * kMaxDet * 4;
        float* kp = out + (size_t)kB * kH * kW + (size_t)kB * kMaxDet * 4 + (size_t)b * kMaxDet;
        int* wsb = paint + b * kMaxDet * 5;
        for (int s = 0; s < kMaxDet; ++s) {
            for (int c = 0; c < 4; ++c) tb[s * 4 + c] = k2[s] ? cb[s][c] : 0.0f;
            kp[s] = k2[s] ? 1.0f : 0.0f;
            wsb[s * 5 + 0] = (int)floorf(cb[s][0] + 0.5f);
            wsb[s * 5 + 1] = (int)floorf(cb[s][1] + 0.5f);
            wsb[s * 5 + 2] = (int)floorf(cb[s][2] + 0.5f);
            wsb[s * 5 + 3] = (int)floorf(cb[s][3] + 0.5f);
            wsb[s * 5 + 4] = k2[s];
        }
    }
}

// ------------- kernel 4: paint coverage mask -------------
__global__ __launch_bounds__(256) void paint_kernel(
    const int* __restrict__ ws, float* __restrict__ out)
{
    int gid = blockIdx.x * 256 + (int)threadIdx.x;  // 4 px each
    int b = gid >> 16;
    int rem = gid & 65535;
    int y = rem >> 7;
    int x0 = (rem & 127) << 2;
    const int* wb = ws + b * kMaxDet * 5;
    float o0 = 1.f, o1 = 1.f, o2 = 1.f, o3 = 1.f;
    #pragma unroll
    for (int s = 0; s < kMaxDet; ++s) {
        int k = wb[s * 5 + 4];
        int y1 = wb[s * 5 + 1], y2 = wb[s * 5 + 3];
        if (k && y >= y1 && y < y2) {
            int x1 = wb[s * 5 + 0], x2 = wb[s * 5 + 2];
            if (x0 + 0 >= x1 && x0 + 0 < x2) o0 = 0.f;
            if (x0 + 1 >= x1 && x0 + 1 < x2) o1 = 0.f;
            if (x0 + 2 >= x1 && x0 + 2 < x2) o2 = 0.f;
            if (x0 + 3 >= x1 && x0 + 3 < x2) o3 = 0.f;
        }
    }
    float4 v = make_float4(o0, o1, o2, o3);
    *((float4*)(out + ((size_t)b << 18) + (y << 9) + x0)) = v;
}

// ------------- fallback: round-1 monolithic kernel (small-ws safety) -------------
__global__ __launch_bounds__(1024) void nms_mono_kernel(
    const float* __restrict__ rbox, const float* __restrict__ negb,
    float* __restrict__ out, int* __restrict__ ws)
{
    __shared__ unsigned long long keys[kNP];
    __shared__ float sx1[kNP], sy1[kNP], sx2[kNP], sy2[kNP], sc[kNP];
    __shared__ unsigned char dead[kNP], kept[kNP];
    __shared__ unsigned long long intra[64];
    __shared__ int chunkIdx[64];
    __shared__ int chunkCnt;
    __shared__ int hasConfSh;
    __shared__ int kidxSh[kMaxDet];
    __shared__ int numSlotsSh;

    const int b = blockIdx.x;
    const int tid = (int)threadIdx.x;
    const int nt = (int)blockDim.x;
    const double M = thrM();
    const float* rb = rbox + (size_t)b * kN * 5;

    for (int i = tid; i < kNP; i += nt) {
        unsigned long long key = 0ull;
        if (i < kN) {
            unsigned u = __float_as_uint(rb[i * 5 + 4]);
            u = (u & 0x80000000u) ? ~u : (u | 0x80000000u);
            key = ((unsigned long long)u << 32) |
                  (unsigned long long)(0xFFFFFFFFu - (unsigned)i);
        }
        keys[i] = key;
        dead[i] = 0; kept[i] = 0;
    }
    __syncthreads();
    for (int k = 2; k <= kNP; k <<= 1) {
        for (int j = k >> 1; j > 0; j >>= 1) {
            for (int i = tid; i < kNP; i += nt) {
                int ixj = i ^ j;
                if (ixj > i) {
                    bool up = ((i & k) != 0);
                    unsigned long long a = keys[i], c = keys[ixj];
                    if ((a > c) == up) { keys[i] = c; keys[ixj] = a; }
                }
            }
            __syncthreads();
        }
    }
    for (int s = tid; s < kNP; s += nt) {
        if (s < kN) {
            unsigned idx = 0xFFFFFFFFu - (unsigned)(keys[s] & 0xFFFFFFFFull);
            const float* p = rb + (size_t)idx * 5;
            sx1[s] = p[0]; sy1[s] = p[1]; sx2[s] = p[2]; sy2[s] = p[3]; sc[s] = p[4];
        } else {
            sx1[s] = 0.f; sy1[s] = 0.f; sx2[s] = 0.f; sy2[s] = 0.f; sc[s] = -1.f;
        }
    }
    __syncthreads();
    float* sar = (float*)keys;
    for (int s = tid; s < kNP; s += nt)
        sar[s] = fmaxf(sx2[s] - sx1[s], 0.f) * fmaxf(sy2[s] - sy1[s], 0.f);
    if (tid == 0) hasConfSh = (sc[0] > kConfT) ? 1 : 0;
    __syncthreads();
    const float confThres = hasConfSh ? kConfT : 0.0f;

    for (int c0 = 0; c0 < kN; c0 += 64) {
        if (tid < 64) {
            int i = c0 + tid;
            unsigned long long m = 0ull;
            if (i < kN) {
                float ax1 = sx1[i], ay1 = sy1[i], ax2 = sx2[i], ay2 = sy2[i], aA = sar[i];
                int jend = min(64, kN - c0);
                for (int jj = tid + 1; jj < jend; ++jj) {
                    int j = c0 + jj;
                    if (iou_suppress(ax1, ay1, ax2, ay2, aA,
                                     sx1[j], sy1[j], sx2[j], sy2[j], sar[j], M))
                        m |= 1ull << jj;
                }
            }
            intra[tid] = m;
        }
        __syncthreads();
        if (tid == 0) {
            int cend = min(64, kN - c0);
            unsigned long long kill = 0ull;
            for (int ii = 0; ii < cend; ++ii)
                if (dead[c0 + ii] || !(sc[c0 + ii] > confThres)) kill |= 1ull << ii;
            unsigned long long sup = 0ull;
            int cnt = 0;
            for (int ii = 0; ii < cend; ++ii) {
                if (!(((kill | sup) >> ii) & 1ull)) {
                    kept[c0 + ii] = 1;
                    chunkIdx[cnt++] = c0 + ii;
                    sup |= intra[ii];
                }
            }
            chunkCnt = cnt;
        }
        __syncthreads();
        int cc = chunkCnt;
        if (cc > 0) {
            for (int j = c0 + 64 + tid; j < kN; j += nt) {
                if (dead[j]) continue;
                float bx1 = sx1[j], by1 = sy1[j], bx2 = sx2[j], by2 = sy2[j], bA = sar[j];
                bool killj = false;
                for (int t = 0; t < cc; ++t) {
                    int i = chunkIdx[t];
                    if (iou_suppress(sx1[i], sy1[i], sx2[i], sy2[i], sar[i],
                                     bx1, by1, bx2, by2, bA, M)) { killj = true; break; }
                }
                if (killj) dead[j] = 1;
            }
        }
        __syncthreads();
    }
    for (int i = tid; i < kN; i += nt) {
        if (kept[i] && !((sx2[i] - sx1[i] >= 1.0f) && (sy2[i] - sy1[i] >= 1.0f)))
            kept[i] = 0;
    }
    __syncthreads();
    if (tid == 0) {
        int limit = hasConfSh ? kMaxDet : kTopK;
        int cnt = 0;
        for (int i = 0; i < kN && cnt < limit; ++i)
            if (kept[i]) kidxSh[cnt++] = i;
        numSlotsSh = cnt;
    }
    __syncthreads();
    if (tid == 0) {
        float comb[kMaxDet][5];
        const float* ng = negb + (size_t)b * kMaxDet * 5;
        int ns = numSlotsSh;
        for (int s = 0; s < kMaxDet; ++s) {
            if (s < ns) {
                int i = kidxSh[s];
                comb[s][0] = sx1[i]; comb[s][1] = sy1[i];
                comb[s][2] = sx2[i]; comb[s][3] = sy2[i]; comb[s][4] = sc[i];
            } else {
                #pragma unroll
                for (int c = 0; c < 5; ++c) comb[s][c] = ng[s * 5 + c];
            }
        }
        int ord[kMaxDet];
        for (int s = 0; s < kMaxDet; ++s) ord[s] = s;
        for (int s = 1; s < kMaxDet; ++s) {
            int cur = ord[s]; float cv = comb[cur][4];
            int t = s - 1;
            while (t >= 0 && comb[ord[t]][4] < cv) { ord[t + 1] = ord[t]; --t; }
            ord[t + 1] = cur;
        }
        float cb[kMaxDet][5];
        for (int s = 0; s < kMaxDet; ++s)
            for (int c = 0; c < 5; ++c) cb[s][c] = comb[ord[s]][c];
        int k2[kMaxDet];
        float ar2[kMaxDet];
        for (int s = 0; s < kMaxDet; ++s) {
            k2[s] = (cb[s][4] > 0.0f) ? 1 : 0;
            ar2[s] = fmaxf(cb[s][2] - cb[s][0], 0.f) * fmaxf(cb[s][3] - cb[s][1], 0.f);
        }
        for (int i = 0; i < kMaxDet; ++i) {
            if (!k2[i]) continue;
            for (int j = i + 1; j < kMaxDet; ++j) {
                if (iou_suppress(cb[i][0], cb[i][1], cb[i][2], cb[i][3], ar2[i],
                                 cb[j][0], cb[j][1], cb[j][2], cb[j][3], ar2[j], M))
                    k2[j] = 0;
            }
        }
        float* tb = out + (size_t)kB * kH * kW + (size_t)b * kMaxDet * 4;
        float* kp = out + (size_t)kB * kH * kW + (size_t)kB * kMaxDet * 4 + (size_t)b * kMaxDet;
        int* wsb = ws + b * kMaxDet * 5;
        for (int s = 0; s < kMaxDet; ++s) {
            for (int c = 0; c < 4; ++c) tb[s * 4 + c] = k2[s] ? cb[s][c] : 0.0f;
            kp[s] = k2[s] ? 1.0f : 0.0f;
            wsb[s * 5 + 0] = (int)floorf(cb[s][0] + 0.5f);
            wsb[s * 5 + 1] = (int)floorf(cb[s][1] + 0.5f);
            wsb[s * 5 + 2] = (int)floorf(cb[s][2] + 0.5f);
            wsb[s * 5 + 3] = (int)floorf(cb[s][3] + 0.5f);
            wsb[s * 5 + 4] = k2[s];
        }
    }
}

extern "C" void kernel_launch(void* const* d_in, const int* in_sizes, int n_in,
                              void* d_out, int out_size, void* d_ws, size_t ws_size,
                              hipStream_t stream)
{
    (void)in_sizes; (void)n_in; (void)out_size;
    const float* rbox = (const float*)d_in[1];   // region_boxes [16,2000,5]
    const float* negb = (const float*)d_in[2];   // neg_boxes   [16,10,5]
    float* out = (float*)d_out;
    char* ws = (char*)d_ws;

    if (ws_size >= WS_NEEDED) {
        float* S = (float*)(ws + OFF_SORT);
        int* paint = (int*)(ws + OFF_PAINT);
        unsigned long long* Mk = (unsigned long long*)(ws + OFF_MASK);
        hipLaunchKernelGGL(sort_kernel, dim3(kB), dim3(1024), 0, stream, rbox, S);
        hipLaunchKernelGGL(mask_kernel, dim3(kNW, kNP / 256, kB), dim3(256), 0, stream, S, Mk);
        hipLaunchKernelGGL(resolve_kernel, dim3(kB), dim3(64), 0, stream, S, Mk, negb, out, paint);
        hipLaunchKernelGGL(paint_kernel, dim3((kB * kH * kW / 4) / 256), dim3(256), 0, stream,
                           paint, out);
    } else {
        int* paint = (int*)ws;
        hipLaunchKernelGGL(nms_mono_kernel, dim3(kB), dim3(1024), 0, stream, rbox, negb, out, paint);
        hipLaunchKernelGGL(paint_kernel, dim3((kB * kH * kW / 4) / 256), dim3(256), 0, stream,
                           paint, out);
    }
}

// Round 3
// 101.589 us; speedup vs baseline: 10.3927x; 2.8617x over previous
//
#include <hip/hip_runtime.h>

namespace {
constexpr int kB = 16;
constexpr int kN = 2000;
constexpr int kH = 512;
constexpr int kW = 512;
constexpr int kMaxDet = 10;
constexpr int kTopK = 5;
constexpr float kConfT = 0.2f;
constexpr int kNT = 256;          // threads per image-block
constexpr int kPB = 8;            // boxes per thread (8*256 = 2048 >= 2000)
}

// Exact test for fl32(inter/denom) > 0.4f without the division:
//   RN(q) > 0.4f  <=>  q >= M, M = midpoint(0.4f, nextup(0.4f))
// (nextup(0.4f) = 0x3ECCCCCE has even mantissa -> the tie rounds up -> include equality).
__device__ __forceinline__ double thrM() {
    return 0.5 * ((double)0.4f + (double)__uint_as_float(0x3ECCCCCEu));
}

__device__ __forceinline__ bool iou_suppress(
    float ax1, float ay1, float ax2, float ay2, float aA,
    float bx1, float by1, float bx2, float by2, float bA, double M)
{
    float ix1 = fmaxf(ax1, bx1), iy1 = fmaxf(ay1, by1);
    float ix2 = fminf(ax2, bx2), iy2 = fminf(ay2, by2);
    float iw = fmaxf(ix2 - ix1, 0.0f), ih = fmaxf(iy2 - iy1, 0.0f);
    // __f*_rn intrinsics: forbid FMA contraction so rounding matches numpy exactly
    float inter = __fmul_rn(iw, ih);
    float denom = __fadd_rn(__fsub_rn(__fadd_rn(aA, bA), inter), 1e-9f);
    return (double)inter >= M * (double)denom;
}

__device__ __forceinline__ unsigned ordmap(float c) {
    unsigned u = __float_as_uint(c);
    return (u & 0x80000000u) ? ~u : (u | 0x80000000u);   // order-preserving float->uint
}

// One block per image. Iterative argmax greedy NMS with early exit at `limit`
// kept-tiny boxes — exactly equivalent to stable-sort + sequential greedy scan:
// the k-th pick is the k-th surviving box in stable descending score order.
__global__ __launch_bounds__(256) void nms_fused(
    const float* __restrict__ rbox,   // [B, N, 5]
    const float* __restrict__ negb,   // [B, 10, 5]
    float* __restrict__ out,          // mask | tboxes | keep2
    int* __restrict__ paint)          // [B,10,5] int for paint kernel
{
    __shared__ float4 cBox[kN];       // 32 KB: x1,y1,x2,y2
    __shared__ float cArea[kN];       // 8 KB
    __shared__ float cConf[kN];       // 8 KB
    __shared__ unsigned long long warg[4];
    __shared__ int hasConfSh;
    __shared__ float keptSh[kMaxDet][5];

    const int b = blockIdx.x;
    const int t = (int)threadIdx.x;
    const int lane = t & 63, wid = t >> 6;
    const double M = thrM();
    const float* rb = rbox + (size_t)b * kN * 5;

    // ---- load: registers (per-thread 8 boxes) + LDS (broadcast by index) ----
    float bx1[kPB], by1[kPB], bx2[kPB], by2[kPB], bar[kPB], bcf[kPB];
    unsigned key[kPB];
    float cmax = -1.0f;
    #pragma unroll
    for (int k = 0; k < kPB; ++k) {
        int j = k * kNT + t;
        float x1 = 0.f, y1 = 0.f, x2 = 0.f, y2 = 0.f, c = -1.f, a = 0.f;
        if (j < kN) {
            const float* p = rb + (size_t)j * 5;
            x1 = p[0]; y1 = p[1]; x2 = p[2]; y2 = p[3]; c = p[4];
            a = __fmul_rn(fmaxf(x2 - x1, 0.f), fmaxf(y2 - y1, 0.f));
            cBox[j] = make_float4(x1, y1, x2, y2);
            cArea[j] = a; cConf[j] = c;
            cmax = fmaxf(cmax, c);
        }
        bx1[k] = x1; by1[k] = y1; bx2[k] = x2; by2[k] = y2; bar[k] = a; bcf[k] = c;
    }
    if (t == 0) hasConfSh = 0;
    __syncthreads();
    if (__any(cmax > kConfT) && lane == 0) hasConfSh = 1;   // benign same-value race
    __syncthreads();
    const int hasConf = hasConfSh;
    const float confThres = hasConf ? kConfT : 0.0f;
    const int limit = hasConf ? kMaxDet : kTopK;

    #pragma unroll
    for (int k = 0; k < kPB; ++k) {
        int j = k * kNT + t;
        key[k] = (j < kN && bcf[k] > confThres) ? ordmap(bcf[k]) : 0u;
    }

    // ---- iterative greedy NMS with early exit ----
    int cnt = 0;
    for (int iter = 0; iter < kN; ++iter) {
        // per-thread argmax over its 8 keys; composite key reproduces stable order
        unsigned long long best = 0ull;
        #pragma unroll
        for (int k = 0; k < kPB; ++k) {
            if (key[k]) {
                unsigned long long cand =
                    ((unsigned long long)key[k] << 32) |
                    (unsigned long long)(0xFFFFFFFFu - (unsigned)(k * kNT + t));
                if (cand > best) best = cand;
            }
        }
        // wave butterfly max
        #pragma unroll
        for (int off = 32; off; off >>= 1) {
            unsigned long long o = __shfl_xor(best, off, 64);
            if (o > best) best = o;
        }
        if (lane == 0) warg[wid] = best;
        __syncthreads();
        unsigned long long w = warg[0];
        if (warg[1] > w) w = warg[1];
        if (warg[2] > w) w = warg[2];
        if (warg[3] > w) w = warg[3];
        if (w == 0ull) break;                       // uniform: no alive valid boxes left
        const int widx = (int)(0xFFFFFFFFu - (unsigned)(w & 0xFFFFFFFFull));
        const float4 wb = cBox[widx];               // LDS broadcast (same addr all lanes)
        const float wa = cArea[widx];

        // tiny filter is applied AFTER NMS: non-tiny kept boxes still suppress
        bool tiny_ok = (wb.z - wb.x >= 1.0f) && (wb.w - wb.y >= 1.0f);
        if (tiny_ok) {
            if (t == 0) {
                keptSh[cnt][0] = wb.x; keptSh[cnt][1] = wb.y;
                keptSh[cnt][2] = wb.z; keptSh[cnt][3] = wb.w;
                keptSh[cnt][4] = cConf[widx];
            }
            ++cnt;                                  // uniform
        }

        // winner suppresses all remaining overlapping boxes (IoU symmetric)
        #pragma unroll
        for (int k = 0; k < kPB; ++k) {
            if (key[k]) {
                int j = k * kNT + t;
                if (j == widx ||
                    iou_suppress(wb.x, wb.y, wb.z, wb.w, wa,
                                 bx1[k], by1[k], bx2[k], by2[k], bar[k], M))
                    key[k] = 0u;
            }
        }
        if (cnt == limit) break;                    // uniform
        __syncthreads();                            // WAR protect warg
    }

    // ---- 10-box stage: combine with neg, stable sort by conf desc, greedy NMS ----
    if (t == 0) {
        float comb[kMaxDet][5];
        const float* ng = negb + (size_t)b * kMaxDet * 5;
        for (int s = 0; s < kMaxDet; ++s) {
            if (s < cnt) {
                #pragma unroll
                for (int c = 0; c < 5; ++c) comb[s][c] = keptSh[s][c];
            } else {
                #pragma unroll
                for (int c = 0; c < 5; ++c) comb[s][c] = ng[s * 5 + c];
            }
        }
        // stable insertion sort, descending conf (== jnp.argsort(-conf), stable)
        int ord[kMaxDet];
        for (int s = 0; s < kMaxDet; ++s) ord[s] = s;
        for (int s = 1; s < kMaxDet; ++s) {
            int cur = ord[s]; float cv = comb[cur][4];
            int q = s - 1;
            while (q >= 0 && comb[ord[q]][4] < cv) { ord[q + 1] = ord[q]; --q; }
            ord[q + 1] = cur;
        }
        float cb[kMaxDet][5];
        for (int s = 0; s < kMaxDet; ++s)
            for (int c = 0; c < 5; ++c) cb[s][c] = comb[ord[s]][c];
        int k2[kMaxDet];
        float ar2[kMaxDet];
        for (int s = 0; s < kMaxDet; ++s) {
            k2[s] = (cb[s][4] > 0.0f) ? 1 : 0;
            ar2[s] = fmaxf(cb[s][2] - cb[s][0], 0.f) * fmaxf(cb[s][3] - cb[s][1], 0.f);
        }
        for (int i = 0; i < kMaxDet; ++i) {
            if (!k2[i]) continue;
            for (int j = i + 1; j < kMaxDet; ++j) {
                if (iou_suppress(cb[i][0], cb[i][1], cb[i][2], cb[i][3], ar2[i],
                                 cb[j][0], cb[j][1], cb[j][2], cb[j][3], ar2[j], M))
                    k2[j] = 0;
            }
        }
        float* tb = out + (size_t)kB * kH * kW + (size_t)b * kMaxDet * 4;
        float* kp = out + (size_t)kB * kH * kW + (size_t)kB * kMaxDet * 4 + (size_t)b * kMaxDet;
        int* wsb = paint + b * kMaxDet * 5;
        for (int s = 0; s < kMaxDet; ++s) {
            for (int c = 0; c < 4; ++c) tb[s * 4 + c] = k2[s] ? cb[s][c] : 0.0f;
            kp[s] = k2[s] ? 1.0f : 0.0f;
            wsb[s * 5 + 0] = (int)floorf(cb[s][0] + 0.5f);
            wsb[s * 5 + 1] = (int)floorf(cb[s][1] + 0.5f);
            wsb[s * 5 + 2] = (int)floorf(cb[s][2] + 0.5f);
            wsb[s * 5 + 3] = (int)floorf(cb[s][3] + 0.5f);
            wsb[s * 5 + 4] = k2[s];
        }
    }
}

// mask_map = 1.0 where NOT covered by any kept box. float4 stores.
__global__ __launch_bounds__(256) void paint_kernel(
    const int* __restrict__ ws, float* __restrict__ out)
{
    int gid = blockIdx.x * 256 + (int)threadIdx.x;  // 4 px each
    int b = gid >> 16;
    int rem = gid & 65535;
    int y = rem >> 7;
    int x0 = (rem & 127) << 2;
    const int* wb = ws + b * kMaxDet * 5;
    float o0 = 1.f, o1 = 1.f, o2 = 1.f, o3 = 1.f;
    #pragma unroll
    for (int s = 0; s < kMaxDet; ++s) {
        int k = wb[s * 5 + 4];
        int y1 = wb[s * 5 + 1], y2 = wb[s * 5 + 3];
        if (k && y >= y1 && y < y2) {
            int x1 = wb[s * 5 + 0], x2 = wb[s * 5 + 2];
            if (x0 + 0 >= x1 && x0 + 0 < x2) o0 = 0.f;
            if (x0 + 1 >= x1 && x0 + 1 < x2) o1 = 0.f;
            if (x0 + 2 >= x1 && x0 + 2 < x2) o2 = 0.f;
            if (x0 + 3 >= x1 && x0 + 3 < x2) o3 = 0.f;
        }
    }
    float4 v = make_float4(o0, o1, o2, o3);
    *((float4*)(out + ((size_t)b << 18) + (y << 9) + x0)) = v;
}

extern "C" void kernel_launch(void* const* d_in, const int* in_sizes, int n_in,
                              void* d_out, int out_size, void* d_ws, size_t ws_size,
                              hipStream_t stream)
{
    (void)in_sizes; (void)n_in; (void)out_size; (void)ws_size;
    const float* rbox = (const float*)d_in[1];   // region_boxes [16,2000,5]
    const float* negb = (const float*)d_in[2];   // neg_boxes   [16,10,5]
    float* out = (float*)d_out;
    int* paint = (int*)d_ws;

    hipLaunchKernelGGL(nms_fused, dim3(kB), dim3(kNT), 0, stream, rbox, negb, out, paint);
    hipLaunchKernelGGL(paint_kernel, dim3((kB * kH * kW / 4) / 256), dim3(256), 0, stream,
                       paint, out);
}